// Round 1
// baseline (967.920 us; speedup 1.0000x reference)
//
#include <hip/hip_runtime.h>
#include <cmath>

#define NFEAT 256
#define NHID  128
#define NCLASS 40

// ---------------- graph preprocessing ----------------

__global__ void k_count(const int* __restrict__ dst, int* __restrict__ cnt, int E){
  int e = blockIdx.x*256 + threadIdx.x;
  if(e < E) atomicAdd(&cnt[dst[e]], 1);
}

__global__ void k_dis(const int* __restrict__ cnt, float* __restrict__ dis, int N){
  int i = blockIdx.x*256 + threadIdx.x;
  if(i < N) dis[i] = rsqrtf((float)(cnt[i] + 1));  // +1 self-loop; >=1 so no max needed
}

__global__ void k_scan1(const int* __restrict__ cnt, int* __restrict__ bsum, int N){
  __shared__ int sd[256];
  int base = blockIdx.x * 1024;
  int s = 0;
  for(int i = threadIdx.x; i < 1024; i += 256){
    int idx = base + i;
    if(idx < N) s += cnt[idx];
  }
  sd[threadIdx.x] = s; __syncthreads();
  for(int o = 128; o > 0; o >>= 1){
    if(threadIdx.x < o) sd[threadIdx.x] += sd[threadIdx.x + o];
    __syncthreads();
  }
  if(threadIdx.x == 0) bsum[blockIdx.x] = sd[0];
}

__global__ void k_scan2(int* bsum, int nb, int* off, int N){
  if(blockIdx.x == 0 && threadIdx.x == 0){
    int run = 0;
    for(int i = 0; i < nb; i++){ int t = bsum[i]; bsum[i] = run; run += t; }
    off[N] = run;
  }
}

__global__ void k_scan3(const int* __restrict__ cnt, const int* __restrict__ bsum,
                        int* __restrict__ off, int* __restrict__ cur, int N){
  __shared__ int sd[256];
  int base = blockIdx.x*1024;
  int i0 = base + threadIdx.x*4;
  int v0=0,v1=0,v2=0,v3=0;
  if(i0+0 < N) v0 = cnt[i0+0];
  if(i0+1 < N) v1 = cnt[i0+1];
  if(i0+2 < N) v2 = cnt[i0+2];
  if(i0+3 < N) v3 = cnt[i0+3];
  int s = v0+v1+v2+v3;
  sd[threadIdx.x] = s; __syncthreads();
  for(int o = 1; o < 256; o <<= 1){
    int val = sd[threadIdx.x];
    int add = (threadIdx.x >= o) ? sd[threadIdx.x - o] : 0;
    __syncthreads();
    sd[threadIdx.x] = val + add;
    __syncthreads();
  }
  int excl = (threadIdx.x == 0) ? 0 : sd[threadIdx.x - 1];
  int run = bsum[blockIdx.x] + excl;
  if(i0+0 < N){ off[i0+0] = run; cur[i0+0] = run; run += v0; }
  if(i0+1 < N){ off[i0+1] = run; cur[i0+1] = run; run += v1; }
  if(i0+2 < N){ off[i0+2] = run; cur[i0+2] = run; run += v2; }
  if(i0+3 < N){ off[i0+3] = run; cur[i0+3] = run; run += v3; }
}

__global__ void k_fill(const int* __restrict__ src, const int* __restrict__ dst,
                       int* __restrict__ cur, int* __restrict__ csr, int E){
  int e = blockIdx.x*256 + threadIdx.x;
  if(e < E){
    int d = dst[e];
    int p = atomicAdd(&cur[d], 1);
    csr[p] = src[e];
  }
}

// ---------------- GEMM (fp32 vector ALU), epilogue scales row r by dis[r] ----------------
// C[M x NOUT] = A[M x K] @ W[K x NOUT], then C[r,:] *= dis[r]

template<int K, int NOUT>
__global__ __launch_bounds__(256)
void gemm_scale(const float* __restrict__ A, const float* __restrict__ W,
                const float* __restrict__ dis, float* __restrict__ C, int M)
{
  constexpr int BM = 128, BN = 64, BK = 16;
  __shared__ float As[BK][BM + 4];
  __shared__ float Ws[BK][BN];
  const int tid = threadIdx.x;
  const int tr = tid & 15;   // row group: 8 rows each
  const int tc = tid >> 4;   // col group: 4 cols each
  const int m0 = blockIdx.x * BM;
  const int n0 = blockIdx.y * BN;

  float acc[8][4];
  #pragma unroll
  for(int i = 0; i < 8; i++)
    #pragma unroll
    for(int j = 0; j < 4; j++) acc[i][j] = 0.f;

  for(int k0 = 0; k0 < K; k0 += BK){
    // stage A tile: 128 rows x 16 k
    #pragma unroll
    for(int j = 0; j < 2; j++){
      int idx = tid + j*256;          // 0..511
      int row = idx & 127;
      int kq  = idx >> 7;             // 0..3
      float4 v = {0.f,0.f,0.f,0.f};
      int grow = m0 + row;
      if(grow < M) v = *reinterpret_cast<const float4*>(&A[(size_t)grow*K + k0 + kq*4]);
      As[kq*4+0][row] = v.x; As[kq*4+1][row] = v.y;
      As[kq*4+2][row] = v.z; As[kq*4+3][row] = v.w;
    }
    // stage W tile: 16 k x 64 cols (zero-pad cols >= NOUT)
    {
      int row = tid >> 4;             // 0..15
      int cq  = tid & 15;             // 0..15
      int col = n0 + cq*4;
      float4 v = {0.f,0.f,0.f,0.f};
      if(col + 3 < NOUT) v = *reinterpret_cast<const float4*>(&W[(size_t)(k0+row)*NOUT + col]);
      *reinterpret_cast<float4*>(&Ws[row][cq*4]) = v;
    }
    __syncthreads();
    #pragma unroll
    for(int k = 0; k < BK; k++){
      float4 a0 = *reinterpret_cast<const float4*>(&As[k][tr*8]);
      float4 a1 = *reinterpret_cast<const float4*>(&As[k][tr*8 + 4]);
      float4 bv = *reinterpret_cast<const float4*>(&Ws[k][tc*4]);
      float a[8] = {a0.x,a0.y,a0.z,a0.w,a1.x,a1.y,a1.z,a1.w};
      float b[4] = {bv.x,bv.y,bv.z,bv.w};
      #pragma unroll
      for(int i = 0; i < 8; i++)
        #pragma unroll
        for(int j = 0; j < 4; j++)
          acc[i][j] += a[i]*b[j];
    }
    __syncthreads();
  }
  #pragma unroll
  for(int i = 0; i < 8; i++){
    int grow = m0 + tr*8 + i;
    if(grow >= M) continue;
    int col = n0 + tc*4;
    if(col >= NOUT) continue;       // NOUT=40: tc>=10 has nothing to write
    float d = dis[grow];
    float4 v;
    v.x = acc[i][0]*d; v.y = acc[i][1]*d; v.z = acc[i][2]*d; v.w = acc[i][3]*d;
    *reinterpret_cast<float4*>(&C[(size_t)grow*NOUT + col]) = v;
  }
}

// ---------------- aggregation: one wave per node ----------------
// T rows already scaled by dis[row]. out = relu(dis[i]*(sum_{u in N(i)} T[u] + T[i]) + b)

__global__ __launch_bounds__(256)
void agg_relu128(const float* __restrict__ T, const int* __restrict__ off,
                 const int* __restrict__ csr, const float* __restrict__ dis,
                 const float* __restrict__ bias, float* __restrict__ H, int N)
{
  int node = blockIdx.x*4 + (threadIdx.x >> 6);
  if(node >= N) return;
  int lane = threadIdx.x & 63;
  int s = off[node], e = off[node+1];
  const float2* T2 = (const float2*)T;
  float2 self = T2[(size_t)node*64 + lane];
  float ax = self.x, ay = self.y;
  int i = s;
  int u_next = (i < e) ? csr[i] : 0;
  for(; i < e; i++){
    int u = u_next;
    if(i + 1 < e) u_next = csr[i+1];
    float2 v = T2[(size_t)u*64 + lane];
    ax += v.x; ay += v.y;
  }
  float di = dis[node];
  float2 b = ((const float2*)bias)[lane];
  float2 o;
  o.x = fmaxf(di*ax + b.x, 0.f);
  o.y = fmaxf(di*ay + b.y, 0.f);
  ((float2*)H)[(size_t)node*64 + lane] = o;
}

__global__ __launch_bounds__(256)
void agg_softmax40(const float* __restrict__ T, const int* __restrict__ off,
                   const int* __restrict__ csr, const float* __restrict__ dis,
                   const float* __restrict__ bias, float* __restrict__ OUT, int N)
{
  int node = blockIdx.x*4 + (threadIdx.x >> 6);
  if(node >= N) return;
  int lane = threadIdx.x & 63;
  int s = off[node], e = off[node+1];
  float acc = 0.f;
  if(lane < NCLASS) acc = T[(size_t)node*NCLASS + lane];
  int i = s;
  int u_next = (i < e) ? csr[i] : 0;
  for(; i < e; i++){
    int u = u_next;
    if(i + 1 < e) u_next = csr[i+1];
    if(lane < NCLASS) acc += T[(size_t)u*NCLASS + lane];
  }
  float di = dis[node];
  float v = (lane < NCLASS) ? (di*acc + bias[lane]) : -1e30f;
  float m = v;
  #pragma unroll
  for(int o = 1; o < 64; o <<= 1) m = fmaxf(m, __shfl_xor(m, o, 64));
  float ex = (lane < NCLASS) ? expf(v - m) : 0.f;
  float ssum = ex;
  #pragma unroll
  for(int o = 1; o < 64; o <<= 1) ssum += __shfl_xor(ssum, o, 64);
  float lse = m + logf(ssum);
  if(lane < NCLASS) OUT[(size_t)node*NCLASS + lane] = v - lse;
}

// ---------------- history overwrite: deterministic "last j wins" ----------------

__global__ void k_stamp(const int* __restrict__ idx_com, int* __restrict__ stamp, int n){
  int j = blockIdx.x*256 + threadIdx.x;
  if(j < n) atomicMax(&stamp[idx_com[j]], j);
}

__global__ __launch_bounds__(256)
void k_overwrite(const int* __restrict__ idx_com, const int* __restrict__ idx_data,
                 const int* __restrict__ stamp, const float* __restrict__ hist,
                 float* __restrict__ H, int n)
{
  int j = blockIdx.x*4 + (threadIdx.x >> 6);
  if(j >= n) return;
  int lane = threadIdx.x & 63;
  int c = idx_com[j];
  if(stamp[c] != j) return;
  int d = idx_data[j];
  ((float2*)H)[(size_t)c*64 + lane] = ((const float2*)hist)[(size_t)d*64 + lane];
}

// ---------------- launch ----------------

extern "C" void kernel_launch(void* const* d_in, const int* in_sizes, int n_in,
                              void* d_out, int out_size, void* d_ws, size_t ws_size,
                              hipStream_t stream)
{
  const float* x    = (const float*)d_in[0];
  const float* W0   = (const float*)d_in[1];
  const float* b0   = (const float*)d_in[2];
  const float* W1   = (const float*)d_in[3];
  const float* b1   = (const float*)d_in[4];
  const float* W2   = (const float*)d_in[5];
  const float* b2   = (const float*)d_in[6];
  const float* hist0 = (const float*)d_in[7];
  const float* hist1 = (const float*)d_in[8];
  const int* esrc = (const int*)d_in[9];
  const int* edst = (const int*)d_in[10];
  const int* idx_data0 = (const int*)d_in[11];
  const int* idx_com0  = (const int*)d_in[12];
  const int* idx_data1 = (const int*)d_in[13];
  const int* idx_com1  = (const int*)d_in[14];

  const int N  = in_sizes[0] / NFEAT;
  const int E  = in_sizes[9];
  const int NC = in_sizes[11];

  // workspace carve-up (all 256B-aligned)
  char* p = (char*)d_ws;
  auto carve = [&](size_t bytes) -> void* {
    void* r = (void*)p;
    p += (bytes + 255) & ~(size_t)255;
    return r;
  };
  int*   cnt  = (int*)  carve((size_t)N*4);
  int*   off  = (int*)  carve((size_t)(N+1)*4);
  int*   cur  = (int*)  carve((size_t)N*4);     // cursor, later stamp
  int*   bsum = (int*)  carve(1024*4);
  int*   csr  = (int*)  carve((size_t)E*4);
  float* dis  = (float*)carve((size_t)N*4);
  float* bufA = (float*)carve((size_t)N*NHID*4);
  float* bufB = (float*)carve((size_t)N*NHID*4);
  float* bufC = (float*)carve((size_t)N*NCLASS*4);

  const int nb = (N + 1023) / 1024;

  hipMemsetAsync(cnt, 0, (size_t)N*4, stream);
  k_count<<<(E+255)/256, 256, 0, stream>>>(edst, cnt, E);
  k_dis  <<<(N+255)/256, 256, 0, stream>>>(cnt, dis, N);
  k_scan1<<<nb, 256, 0, stream>>>(cnt, bsum, N);
  k_scan2<<<1, 256, 0, stream>>>(bsum, nb, off, N);
  k_scan3<<<nb, 256, 0, stream>>>(cnt, bsum, off, cur, N);
  k_fill <<<(E+255)/256, 256, 0, stream>>>(esrc, edst, cur, csr, E);

  dim3 g0((N + 127)/128, 2);
  gemm_scale<NFEAT, NHID><<<g0, 256, 0, stream>>>(x, W0, dis, bufA, N);
  agg_relu128<<<(N+3)/4, 256, 0, stream>>>(bufA, off, csr, dis, b0, bufB, N);

  hipMemsetAsync(cur, 0xFF, (size_t)N*4, stream);
  k_stamp<<<(NC+255)/256, 256, 0, stream>>>(idx_com0, cur, NC);
  k_overwrite<<<(NC+3)/4, 256, 0, stream>>>(idx_com0, idx_data0, cur, hist0, bufB, NC);

  dim3 g1((N + 127)/128, 2);
  gemm_scale<NHID, NHID><<<g1, 256, 0, stream>>>(bufB, W1, dis, bufA, N);
  agg_relu128<<<(N+3)/4, 256, 0, stream>>>(bufA, off, csr, dis, b1, bufB, N);

  hipMemsetAsync(cur, 0xFF, (size_t)N*4, stream);
  k_stamp<<<(NC+255)/256, 256, 0, stream>>>(idx_com1, cur, NC);
  k_overwrite<<<(NC+3)/4, 256, 0, stream>>>(idx_com1, idx_data1, cur, hist1, bufB, NC);

  dim3 g2((N + 127)/128, 1);
  gemm_scale<NHID, NCLASS><<<g2, 256, 0, stream>>>(bufB, W2, dis, bufC, N);
  agg_softmax40<<<(N+3)/4, 256, 0, stream>>>(bufC, off, csr, dis, b2, (float*)d_out, N);
}

// Round 2
// 797.771 us; speedup vs baseline: 1.2133x; 1.2133x over previous
//
#include <hip/hip_runtime.h>
#include <cmath>

#define NFEAT 256
#define NHID  128
#define NCLASS 40
#define MAXNB 800      // buckets of 128 nodes: ceil(100000/128)=782
#define CHUNK 8192

// ================= graph preprocessing: bucketed CSR build =================
// bucket b = dst >> 7  (128 nodes per bucket)

__global__ __launch_bounds__(256)
void P1_hist(const int* __restrict__ dst, int* __restrict__ bh, int E, int NB){
  __shared__ int lh[MAXNB];
  for(int t = threadIdx.x; t < NB; t += 256) lh[t] = 0;
  __syncthreads();
  for(int i = blockIdx.x*256 + threadIdx.x; i < E; i += gridDim.x*256)
    atomicAdd(&lh[dst[i] >> 7], 1);
  __syncthreads();
  for(int t = threadIdx.x; t < NB; t += 256){
    int c = lh[t];
    if(c) atomicAdd(&bh[t], c);
  }
}

__global__ __launch_bounds__(1024)
void P2_scan(const int* __restrict__ bh, int* __restrict__ boff, int* __restrict__ bcur,
             int* __restrict__ off, int N, int E, int NB){
  __shared__ int sc[1024];
  int t = threadIdx.x;
  int v = (t < NB) ? bh[t] : 0;
  sc[t] = v; __syncthreads();
  for(int o = 1; o < 1024; o <<= 1){
    int a = sc[t] + ((t >= o) ? sc[t-o] : 0);
    __syncthreads();
    sc[t] = a;
    __syncthreads();
  }
  int ex = sc[t] - v;          // exclusive scan
  if(t < NB){ boff[t] = ex; bcur[t] = ex; }
  if(t == 0){ boff[NB] = E; off[N] = E; }
}

// partition edges into bucket order; per-block chunk reservation -> coalesced runs
__global__ __launch_bounds__(256)
void P3_part(const int* __restrict__ src, const int* __restrict__ dst,
             int* __restrict__ bcur, int2* __restrict__ tmp, int E, int NB){
  __shared__ int dstS[CHUNK];
  __shared__ int lh[MAXNB];
  __shared__ int lcur[MAXNB];
  int base = blockIdx.x * CHUNK;
  int n = E - base; if(n > CHUNK) n = CHUNK;
  for(int t = threadIdx.x; t < NB; t += 256){ lh[t] = 0; lcur[t] = 0; }
  __syncthreads();
  for(int j = threadIdx.x; j < n; j += 256){
    int d = dst[base + j];
    dstS[j] = d;
    atomicAdd(&lh[d >> 7], 1);
  }
  __syncthreads();
  for(int t = threadIdx.x; t < NB; t += 256){
    int c = lh[t];
    if(c) lh[t] = atomicAdd(&bcur[t], c);   // reserve contiguous run; lh now = base pos
  }
  __syncthreads();
  for(int j = threadIdx.x; j < n; j += 256){
    int d = dstS[j];
    int b = d >> 7;
    int p = lh[b] + atomicAdd(&lcur[b], 1);
    tmp[p] = make_int2(src[base + j], d);
  }
}

// per-bucket: exact per-node offsets, dis, and CSR placement (block-local writes)
__global__ __launch_bounds__(256)
void P4_build(const int2* __restrict__ tmp, const int* __restrict__ boff,
              int* __restrict__ off, float* __restrict__ dis,
              int* __restrict__ csr, int N){
  __shared__ int2 eS[3072];
  __shared__ int cnt[128], sc[128], cur[128];
  int b = blockIdx.x;
  int s = boff[b], e = boff[b+1];
  int ne = e - s;
  int n0 = b * 128;
  if(threadIdx.x < 128){ cnt[threadIdx.x] = 0; cur[threadIdx.x] = 0; }
  __syncthreads();
  bool fits = (ne <= 3072);
  for(int i = threadIdx.x; i < ne; i += 256){
    int2 p = tmp[s + i];
    if(fits) eS[i] = p;
    atomicAdd(&cnt[p.y & 127], 1);
  }
  __syncthreads();
  if(threadIdx.x < 128) sc[threadIdx.x] = cnt[threadIdx.x];
  __syncthreads();
  for(int o = 1; o < 128; o <<= 1){
    int a = 0;
    if(threadIdx.x < 128) a = sc[threadIdx.x] + ((threadIdx.x >= o) ? sc[threadIdx.x - o] : 0);
    __syncthreads();
    if(threadIdx.x < 128) sc[threadIdx.x] = a;
    __syncthreads();
  }
  if(threadIdx.x < 128){
    int node = n0 + threadIdx.x;
    if(node < N){
      int c = cnt[threadIdx.x];
      off[node] = s + sc[threadIdx.x] - c;       // exclusive
      dis[node] = rsqrtf((float)(c + 1));        // +1 self-loop
    }
  }
  __syncthreads();
  for(int i = threadIdx.x; i < ne; i += 256){
    int2 p = fits ? eS[i] : tmp[s + i];
    int l = p.y & 127;
    int pos = s + (sc[l] - cnt[l]) + atomicAdd(&cur[l], 1);
    csr[pos] = p.x;
  }
}

// ================= GEMM (fp32 vector ALU), row r scaled by dis[r] =================

template<int K, int NOUT>
__global__ __launch_bounds__(256)
void gemm_scale(const float* __restrict__ A, const float* __restrict__ W,
                const float* __restrict__ dis, float* __restrict__ C, int M)
{
  constexpr int BM = 128, BN = 64, BK = 16;
  __shared__ float As[BK][BM + 4];
  __shared__ float Ws[BK][BN];
  const int tid = threadIdx.x;
  const int tr = tid & 15;
  const int tc = tid >> 4;
  const int m0 = blockIdx.x * BM;
  const int n0 = blockIdx.y * BN;

  float acc[8][4];
  #pragma unroll
  for(int i = 0; i < 8; i++)
    #pragma unroll
    for(int j = 0; j < 4; j++) acc[i][j] = 0.f;

  for(int k0 = 0; k0 < K; k0 += BK){
    #pragma unroll
    for(int j = 0; j < 2; j++){
      int idx = tid + j*256;
      int row = idx & 127;
      int kq  = idx >> 7;
      float4 v = {0.f,0.f,0.f,0.f};
      int grow = m0 + row;
      if(grow < M) v = *reinterpret_cast<const float4*>(&A[(size_t)grow*K + k0 + kq*4]);
      As[kq*4+0][row] = v.x; As[kq*4+1][row] = v.y;
      As[kq*4+2][row] = v.z; As[kq*4+3][row] = v.w;
    }
    {
      int row = tid >> 4;
      int cq  = tid & 15;
      int col = n0 + cq*4;
      float4 v = {0.f,0.f,0.f,0.f};
      if(col + 3 < NOUT) v = *reinterpret_cast<const float4*>(&W[(size_t)(k0+row)*NOUT + col]);
      *reinterpret_cast<float4*>(&Ws[row][cq*4]) = v;
    }
    __syncthreads();
    #pragma unroll
    for(int k = 0; k < BK; k++){
      float4 a0 = *reinterpret_cast<const float4*>(&As[k][tr*8]);
      float4 a1 = *reinterpret_cast<const float4*>(&As[k][tr*8 + 4]);
      float4 bv = *reinterpret_cast<const float4*>(&Ws[k][tc*4]);
      float a[8] = {a0.x,a0.y,a0.z,a0.w,a1.x,a1.y,a1.z,a1.w};
      float bb[4] = {bv.x,bv.y,bv.z,bv.w};
      #pragma unroll
      for(int i = 0; i < 8; i++)
        #pragma unroll
        for(int j = 0; j < 4; j++)
          acc[i][j] += a[i]*bb[j];
    }
    __syncthreads();
  }
  #pragma unroll
  for(int i = 0; i < 8; i++){
    int grow = m0 + tr*8 + i;
    if(grow >= M) continue;
    int col = n0 + tc*4;
    if(col >= NOUT) continue;
    float d = dis[grow];
    float4 v;
    v.x = acc[i][0]*d; v.y = acc[i][1]*d; v.z = acc[i][2]*d; v.w = acc[i][3]*d;
    *reinterpret_cast<float4*>(&C[(size_t)grow*NOUT + col]) = v;
  }
}

// ================= aggregation =================
// one wave per node, 2 neighbors/iter, float4 lanes (32 slots x 16B = 512B row)

__global__ __launch_bounds__(256)
void agg_relu128(const float* __restrict__ T, const int* __restrict__ off,
                 const int* __restrict__ csr, const float* __restrict__ dis,
                 const float* __restrict__ bias, float* __restrict__ H, int N)
{
  int node = blockIdx.x*4 + (threadIdx.x >> 6);
  if(node >= N) return;
  int lane = threadIdx.x & 63;
  int half = lane >> 5;
  int sl = lane & 31;
  int s = off[node], e = off[node+1];
  const float4* T4 = (const float4*)T;
  float4 acc = {0.f,0.f,0.f,0.f};
  for(int i = s + half; i < e; i += 2){
    int u = csr[i];
    float4 v = T4[(size_t)u*32 + sl];
    acc.x += v.x; acc.y += v.y; acc.z += v.z; acc.w += v.w;
  }
  if(half == 0){
    float4 v = T4[(size_t)node*32 + sl];
    acc.x += v.x; acc.y += v.y; acc.z += v.z; acc.w += v.w;
  }
  acc.x += __shfl_down(acc.x, 32, 64);
  acc.y += __shfl_down(acc.y, 32, 64);
  acc.z += __shfl_down(acc.z, 32, 64);
  acc.w += __shfl_down(acc.w, 32, 64);
  if(lane < 32){
    float di = dis[node];
    float4 b = ((const float4*)bias)[sl];
    float4 o;
    o.x = fmaxf(di*acc.x + b.x, 0.f);
    o.y = fmaxf(di*acc.y + b.y, 0.f);
    o.z = fmaxf(di*acc.z + b.z, 0.f);
    o.w = fmaxf(di*acc.w + b.w, 0.f);
    ((float4*)H)[(size_t)node*32 + sl] = o;
  }
}

// one wave per node; 3 neighbors/iter across 20-lane float2 groups
__global__ __launch_bounds__(256)
void agg_softmax40(const float* __restrict__ T, const int* __restrict__ off,
                   const int* __restrict__ csr, const float* __restrict__ dis,
                   const float* __restrict__ bias, float* __restrict__ OUT, int N)
{
  int node = blockIdx.x*4 + (threadIdx.x >> 6);
  if(node >= N) return;
  int lane = threadIdx.x & 63;
  int g  = lane / 20;          // 0..2 valid, 3 = idle lanes 60..63
  int sl = lane - g*20;        // 0..19
  int s = off[node], e = off[node+1];
  const float2* T2 = (const float2*)T;
  float ax = 0.f, ay = 0.f;
  if(g < 3){
    for(int i = s + g; i < e; i += 3){
      int u = csr[i];
      float2 v = T2[(size_t)u*20 + sl];
      ax += v.x; ay += v.y;
    }
    if(g == 0){
      float2 v = T2[(size_t)node*20 + sl];
      ax += v.x; ay += v.y;
    }
  }
  // combine the 3 groups into lanes 0..19
  ax += __shfl(ax, lane + 20, 64) + __shfl(ax, lane + 40, 64);
  ay += __shfl(ay, lane + 20, 64) + __shfl(ay, lane + 40, 64);
  float di = dis[node];
  float vx = -1e30f, vy = -1e30f;
  if(lane < 20){
    float2 b = ((const float2*)bias)[sl];
    vx = di*ax + b.x;
    vy = di*ay + b.y;
  }
  float m = fmaxf(vx, vy);
  #pragma unroll
  for(int o = 1; o < 32; o <<= 1) m = fmaxf(m, __shfl_xor(m, o, 32));
  float ex = (lane < 20) ? (expf(vx - m) + expf(vy - m)) : 0.f;
  float ssum = ex;
  #pragma unroll
  for(int o = 1; o < 32; o <<= 1) ssum += __shfl_xor(ssum, o, 32);
  float lse = m + logf(ssum);
  if(lane < 20){
    float2 o2; o2.x = vx - lse; o2.y = vy - lse;
    ((float2*)OUT)[(size_t)node*20 + sl] = o2;
  }
}

// ================= history overwrite: deterministic "last j wins" =================

__global__ void k_stamp(const int* __restrict__ idx_com, int* __restrict__ stamp, int n){
  int j = blockIdx.x*256 + threadIdx.x;
  if(j < n) atomicMax(&stamp[idx_com[j]], j);
}

__global__ __launch_bounds__(256)
void k_overwrite(const int* __restrict__ idx_com, const int* __restrict__ idx_data,
                 const int* __restrict__ stamp, const float* __restrict__ hist,
                 float* __restrict__ H, int n)
{
  int j = blockIdx.x*4 + (threadIdx.x >> 6);
  if(j >= n) return;
  int lane = threadIdx.x & 63;
  int c = idx_com[j];
  if(stamp[c] != j) return;
  int d = idx_data[j];
  ((float2*)H)[(size_t)c*64 + lane] = ((const float2*)hist)[(size_t)d*64 + lane];
}

// ================= launch =================

extern "C" void kernel_launch(void* const* d_in, const int* in_sizes, int n_in,
                              void* d_out, int out_size, void* d_ws, size_t ws_size,
                              hipStream_t stream)
{
  const float* x     = (const float*)d_in[0];
  const float* W0    = (const float*)d_in[1];
  const float* b0    = (const float*)d_in[2];
  const float* W1    = (const float*)d_in[3];
  const float* b1    = (const float*)d_in[4];
  const float* W2    = (const float*)d_in[5];
  const float* b2    = (const float*)d_in[6];
  const float* hist0 = (const float*)d_in[7];
  const float* hist1 = (const float*)d_in[8];
  const int* esrc = (const int*)d_in[9];
  const int* edst = (const int*)d_in[10];
  const int* idx_data0 = (const int*)d_in[11];
  const int* idx_com0  = (const int*)d_in[12];
  const int* idx_data1 = (const int*)d_in[13];
  const int* idx_com1  = (const int*)d_in[14];

  const int N  = in_sizes[0] / NFEAT;
  const int E  = in_sizes[9];
  const int NC = in_sizes[11];
  const int NB = (N + 127) / 128;

  char* p = (char*)d_ws;
  auto carve = [&](size_t bytes) -> void* {
    void* r = (void*)p;
    p += (bytes + 255) & ~(size_t)255;
    return r;
  };
  int*   bh    = (int*)  carve((size_t)NB*4);
  int*   boff  = (int*)  carve((size_t)(NB+1)*4);
  int*   bcur  = (int*)  carve((size_t)NB*4);
  int*   off   = (int*)  carve((size_t)(N+1)*4);
  int*   stamp = (int*)  carve((size_t)N*4);
  int*   csr   = (int*)  carve((size_t)E*4);
  float* dis   = (float*)carve((size_t)N*4);
  float* bufA  = (float*)carve((size_t)N*NHID*4);
  float* bufB  = (float*)carve((size_t)N*NHID*4);
  // bufC (N*NCLASS floats = 16MB) overlays partition tmp (E int2 = 12.8MB)
  size_t cbytes = (size_t)N*NCLASS*4;
  size_t tbytes = (size_t)E*8;
  float* bufC  = (float*)carve(cbytes > tbytes ? cbytes : tbytes);
  int2*  tmp   = (int2*)bufC;

  // --- build CSR + degrees ---
  hipMemsetAsync(bh, 0, (size_t)NB*4, stream);
  P1_hist<<<256, 256, 0, stream>>>(edst, bh, E, NB);
  P2_scan<<<1, 1024, 0, stream>>>(bh, boff, bcur, off, N, E, NB);
  P3_part<<<(E + CHUNK - 1)/CHUNK, 256, 0, stream>>>(esrc, edst, bcur, tmp, E, NB);
  P4_build<<<NB, 256, 0, stream>>>(tmp, boff, off, dis, csr, N);

  // --- layer 0 ---
  dim3 g0((N + 127)/128, 2);
  gemm_scale<NFEAT, NHID><<<g0, 256, 0, stream>>>(x, W0, dis, bufA, N);
  agg_relu128<<<(N+3)/4, 256, 0, stream>>>(bufA, off, csr, dis, b0, bufB, N);

  hipMemsetAsync(stamp, 0xFF, (size_t)N*4, stream);
  k_stamp<<<(NC+255)/256, 256, 0, stream>>>(idx_com0, stamp, NC);
  k_overwrite<<<(NC+3)/4, 256, 0, stream>>>(idx_com0, idx_data0, stamp, hist0, bufB, NC);

  // --- layer 1 ---
  dim3 g1((N + 127)/128, 2);
  gemm_scale<NHID, NHID><<<g1, 256, 0, stream>>>(bufB, W1, dis, bufA, N);
  agg_relu128<<<(N+3)/4, 256, 0, stream>>>(bufA, off, csr, dis, b1, bufB, N);

  hipMemsetAsync(stamp, 0xFF, (size_t)N*4, stream);
  k_stamp<<<(NC+255)/256, 256, 0, stream>>>(idx_com1, stamp, NC);
  k_overwrite<<<(NC+3)/4, 256, 0, stream>>>(idx_com1, idx_data1, stamp, hist1, bufB, NC);

  // --- layer 2 + log_softmax ---
  dim3 g2((N + 127)/128, 1);
  gemm_scale<NHID, NCLASS><<<g2, 256, 0, stream>>>(bufB, W2, dis, bufC, N);
  agg_softmax40<<<(N+3)/4, 256, 0, stream>>>(bufC, off, csr, dis, b2, (float*)d_out, N);
}

// Round 3
// 777.577 us; speedup vs baseline: 1.2448x; 1.0260x over previous
//
#include <hip/hip_runtime.h>
#include <cmath>

#define NFEAT 256
#define NHID  128
#define NCLASS 40
#define MAXNB 800      // buckets of 128 nodes: ceil(100000/128)=782
#define CHUNK 8192

// ================= graph preprocessing: bucketed CSR build =================

__global__ __launch_bounds__(256)
void P1_hist(const int* __restrict__ dst, int* __restrict__ bh, int E, int NB){
  __shared__ int lh[MAXNB];
  for(int t = threadIdx.x; t < NB; t += 256) lh[t] = 0;
  __syncthreads();
  for(int i = blockIdx.x*256 + threadIdx.x; i < E; i += gridDim.x*256)
    atomicAdd(&lh[dst[i] >> 7], 1);
  __syncthreads();
  for(int t = threadIdx.x; t < NB; t += 256){
    int c = lh[t];
    if(c) atomicAdd(&bh[t], c);
  }
}

__global__ __launch_bounds__(1024)
void P2_scan(const int* __restrict__ bh, int* __restrict__ boff, int* __restrict__ bcur,
             int* __restrict__ off, int N, int E, int NB){
  __shared__ int sc[1024];
  int t = threadIdx.x;
  int v = (t < NB) ? bh[t] : 0;
  sc[t] = v; __syncthreads();
  for(int o = 1; o < 1024; o <<= 1){
    int a = sc[t] + ((t >= o) ? sc[t-o] : 0);
    __syncthreads();
    sc[t] = a;
    __syncthreads();
  }
  int ex = sc[t] - v;
  if(t < NB){ boff[t] = ex; bcur[t] = ex; }
  if(t == 0){ boff[NB] = E; off[N] = E; }
}

__global__ __launch_bounds__(256)
void P3_part(const int* __restrict__ src, const int* __restrict__ dst,
             int* __restrict__ bcur, int2* __restrict__ tmp, int E, int NB){
  __shared__ int dstS[CHUNK];
  __shared__ int lh[MAXNB];
  __shared__ int lcur[MAXNB];
  int base = blockIdx.x * CHUNK;
  int n = E - base; if(n > CHUNK) n = CHUNK;
  for(int t = threadIdx.x; t < NB; t += 256){ lh[t] = 0; lcur[t] = 0; }
  __syncthreads();
  for(int j = threadIdx.x; j < n; j += 256){
    int d = dst[base + j];
    dstS[j] = d;
    atomicAdd(&lh[d >> 7], 1);
  }
  __syncthreads();
  for(int t = threadIdx.x; t < NB; t += 256){
    int c = lh[t];
    if(c) lh[t] = atomicAdd(&bcur[t], c);
  }
  __syncthreads();
  for(int j = threadIdx.x; j < n; j += 256){
    int d = dstS[j];
    int b = d >> 7;
    int p = lh[b] + atomicAdd(&lcur[b], 1);
    tmp[p] = make_int2(src[base + j], d);
  }
}

__global__ __launch_bounds__(256)
void P4_build(const int2* __restrict__ tmp, const int* __restrict__ boff,
              int* __restrict__ off, float* __restrict__ dis,
              int* __restrict__ csr, int N){
  __shared__ int2 eS[3072];
  __shared__ int cnt[128], sc[128], cur[128];
  int b = blockIdx.x;
  int s = boff[b], e = boff[b+1];
  int ne = e - s;
  int n0 = b * 128;
  if(threadIdx.x < 128){ cnt[threadIdx.x] = 0; cur[threadIdx.x] = 0; }
  __syncthreads();
  bool fits = (ne <= 3072);
  for(int i = threadIdx.x; i < ne; i += 256){
    int2 p = tmp[s + i];
    if(fits) eS[i] = p;
    atomicAdd(&cnt[p.y & 127], 1);
  }
  __syncthreads();
  if(threadIdx.x < 128) sc[threadIdx.x] = cnt[threadIdx.x];
  __syncthreads();
  for(int o = 1; o < 128; o <<= 1){
    int a = 0;
    if(threadIdx.x < 128) a = sc[threadIdx.x] + ((threadIdx.x >= o) ? sc[threadIdx.x - o] : 0);
    __syncthreads();
    if(threadIdx.x < 128) sc[threadIdx.x] = a;
    __syncthreads();
  }
  if(threadIdx.x < 128){
    int node = n0 + threadIdx.x;
    if(node < N){
      int c = cnt[threadIdx.x];
      off[node] = s + sc[threadIdx.x] - c;
      dis[node] = rsqrtf((float)(c + 1));
    }
  }
  __syncthreads();
  for(int i = threadIdx.x; i < ne; i += 256){
    int2 p = fits ? eS[i] : tmp[s + i];
    int l = p.y & 127;
    int pos = s + (sc[l] - cnt[l]) + atomicAdd(&cur[l], 1);
    csr[pos] = p.x;
  }
}

// ================= GEMMs (fp32 vector ALU), row r scaled by dis[r] =================

// 128-out GEMM: BM=128 x BN=128, 8x8 micro-tile, fragments at stride-16B (conflict-free)
template<int K>
__global__ __launch_bounds__(256)
void gemm128_scale(const float* __restrict__ A, const float* __restrict__ W,
                   const float* __restrict__ dis, float* __restrict__ C, int M)
{
  constexpr int BM = 128, BK = 16;
  __shared__ float As[BK][BM + 4];
  __shared__ float Ws[BK][128 + 4];
  const int tid = threadIdx.x;
  const int tr = tid >> 4;   // 0..15 row group
  const int tc = tid & 15;   // 0..15 col group
  const int m0 = blockIdx.x * BM;

  float acc[8][8];
  #pragma unroll
  for(int i = 0; i < 8; i++)
    #pragma unroll
    for(int j = 0; j < 8; j++) acc[i][j] = 0.f;

  for(int k0 = 0; k0 < K; k0 += BK){
    #pragma unroll
    for(int j = 0; j < 2; j++){
      int idx = tid + j*256;
      int row = idx & 127;
      int kq  = idx >> 7;
      float4 v = {0.f,0.f,0.f,0.f};
      int gr = m0 + row;
      if(gr < M) v = *reinterpret_cast<const float4*>(&A[(size_t)gr*K + k0 + kq*4]);
      As[kq*4+0][row] = v.x; As[kq*4+1][row] = v.y;
      As[kq*4+2][row] = v.z; As[kq*4+3][row] = v.w;
    }
    #pragma unroll
    for(int j = 0; j < 2; j++){
      int idx = tid + j*256;
      int row = idx >> 5;        // 0..15
      int cq  = idx & 31;        // 0..31
      float4 v = *reinterpret_cast<const float4*>(&W[(size_t)(k0+row)*128 + cq*4]);
      *reinterpret_cast<float4*>(&Ws[row][cq*4]) = v;
    }
    __syncthreads();
    #pragma unroll
    for(int k = 0; k < BK; k++){
      float4 a0 = *reinterpret_cast<const float4*>(&As[k][tr*4]);
      float4 a1 = *reinterpret_cast<const float4*>(&As[k][64 + tr*4]);
      float4 b0 = *reinterpret_cast<const float4*>(&Ws[k][tc*4]);
      float4 b1 = *reinterpret_cast<const float4*>(&Ws[k][64 + tc*4]);
      float a[8] = {a0.x,a0.y,a0.z,a0.w, a1.x,a1.y,a1.z,a1.w};
      float b[8] = {b0.x,b0.y,b0.z,b0.w, b1.x,b1.y,b1.z,b1.w};
      #pragma unroll
      for(int i = 0; i < 8; i++)
        #pragma unroll
        for(int j = 0; j < 8; j++)
          acc[i][j] += a[i]*b[j];
    }
    __syncthreads();
  }
  #pragma unroll
  for(int i = 0; i < 8; i++){
    int gr = m0 + ((i < 4) ? (tr*4 + i) : (64 + tr*4 + (i - 4)));
    if(gr >= M) continue;
    float d = dis[gr];
    float4 v0, v1;
    v0.x = acc[i][0]*d; v0.y = acc[i][1]*d; v0.z = acc[i][2]*d; v0.w = acc[i][3]*d;
    v1.x = acc[i][4]*d; v1.y = acc[i][5]*d; v1.z = acc[i][6]*d; v1.w = acc[i][7]*d;
    *reinterpret_cast<float4*>(&C[(size_t)gr*128 + tc*4]) = v0;
    *reinterpret_cast<float4*>(&C[(size_t)gr*128 + 64 + tc*4]) = v1;
  }
}

// 40-out GEMM (final layer): proven BM=128 x BN=64, 8x4 micro-tile
template<int K, int NOUT>
__global__ __launch_bounds__(256)
void gemm_scale(const float* __restrict__ A, const float* __restrict__ W,
                const float* __restrict__ dis, float* __restrict__ C, int M)
{
  constexpr int BM = 128, BN = 64, BK = 16;
  __shared__ float As[BK][BM + 4];
  __shared__ float Ws[BK][BN];
  const int tid = threadIdx.x;
  const int tr = tid & 15;
  const int tc = tid >> 4;
  const int m0 = blockIdx.x * BM;
  const int n0 = blockIdx.y * BN;

  float acc[8][4];
  #pragma unroll
  for(int i = 0; i < 8; i++)
    #pragma unroll
    for(int j = 0; j < 4; j++) acc[i][j] = 0.f;

  for(int k0 = 0; k0 < K; k0 += BK){
    #pragma unroll
    for(int j = 0; j < 2; j++){
      int idx = tid + j*256;
      int row = idx & 127;
      int kq  = idx >> 7;
      float4 v = {0.f,0.f,0.f,0.f};
      int grow = m0 + row;
      if(grow < M) v = *reinterpret_cast<const float4*>(&A[(size_t)grow*K + k0 + kq*4]);
      As[kq*4+0][row] = v.x; As[kq*4+1][row] = v.y;
      As[kq*4+2][row] = v.z; As[kq*4+3][row] = v.w;
    }
    {
      int row = tid >> 4;
      int cq  = tid & 15;
      int col = n0 + cq*4;
      float4 v = {0.f,0.f,0.f,0.f};
      if(col + 3 < NOUT) v = *reinterpret_cast<const float4*>(&W[(size_t)(k0+row)*NOUT + col]);
      *reinterpret_cast<float4*>(&Ws[row][cq*4]) = v;
    }
    __syncthreads();
    #pragma unroll
    for(int k = 0; k < BK; k++){
      float4 a0 = *reinterpret_cast<const float4*>(&As[k][tr*8]);
      float4 a1 = *reinterpret_cast<const float4*>(&As[k][tr*8 + 4]);
      float4 bv = *reinterpret_cast<const float4*>(&Ws[k][tc*4]);
      float a[8] = {a0.x,a0.y,a0.z,a0.w,a1.x,a1.y,a1.z,a1.w};
      float bb[4] = {bv.x,bv.y,bv.z,bv.w};
      #pragma unroll
      for(int i = 0; i < 8; i++)
        #pragma unroll
        for(int j = 0; j < 4; j++)
          acc[i][j] += a[i]*bb[j];
    }
    __syncthreads();
  }
  #pragma unroll
  for(int i = 0; i < 8; i++){
    int grow = m0 + tr*8 + i;
    if(grow >= M) continue;
    int col = n0 + tc*4;
    if(col >= NOUT) continue;
    float d = dis[grow];
    float4 v;
    v.x = acc[i][0]*d; v.y = acc[i][1]*d; v.z = acc[i][2]*d; v.w = acc[i][3]*d;
    *reinterpret_cast<float4*>(&C[(size_t)grow*NOUT + col]) = v;
  }
}

// ================= aggregation =================
// one wave per node; 2 halves x 4-way unroll = 8 gathers in flight per wave

__global__ __launch_bounds__(256)
void agg_relu128(const float* __restrict__ T, const int* __restrict__ off,
                 const int* __restrict__ csr, const float* __restrict__ dis,
                 const float* __restrict__ bias, float* __restrict__ H, int N)
{
  int node = blockIdx.x*4 + (threadIdx.x >> 6);
  if(node >= N) return;
  int lane = threadIdx.x & 63;
  int half = lane >> 5;
  int sl = lane & 31;
  int s = off[node], e = off[node+1];
  const float4* T4 = (const float4*)T;
  float4 a0 = {0.f,0.f,0.f,0.f}, a1 = a0, a2 = a0, a3 = a0;
  int i = s + half;
  for(; i + 6 < e; i += 8){
    int u0 = csr[i], u1 = csr[i+2], u2 = csr[i+4], u3 = csr[i+6];
    float4 v0 = T4[(size_t)u0*32 + sl];
    float4 v1 = T4[(size_t)u1*32 + sl];
    float4 v2 = T4[(size_t)u2*32 + sl];
    float4 v3 = T4[(size_t)u3*32 + sl];
    a0.x += v0.x; a0.y += v0.y; a0.z += v0.z; a0.w += v0.w;
    a1.x += v1.x; a1.y += v1.y; a1.z += v1.z; a1.w += v1.w;
    a2.x += v2.x; a2.y += v2.y; a2.z += v2.z; a2.w += v2.w;
    a3.x += v3.x; a3.y += v3.y; a3.z += v3.z; a3.w += v3.w;
  }
  for(; i < e; i += 2){
    int u = csr[i];
    float4 v = T4[(size_t)u*32 + sl];
    a0.x += v.x; a0.y += v.y; a0.z += v.z; a0.w += v.w;
  }
  if(half == 0){
    float4 v = T4[(size_t)node*32 + sl];
    a0.x += v.x; a0.y += v.y; a0.z += v.z; a0.w += v.w;
  }
  float4 acc;
  acc.x = a0.x + a1.x + a2.x + a3.x;
  acc.y = a0.y + a1.y + a2.y + a3.y;
  acc.z = a0.z + a1.z + a2.z + a3.z;
  acc.w = a0.w + a1.w + a2.w + a3.w;
  acc.x += __shfl_down(acc.x, 32, 64);
  acc.y += __shfl_down(acc.y, 32, 64);
  acc.z += __shfl_down(acc.z, 32, 64);
  acc.w += __shfl_down(acc.w, 32, 64);
  if(lane < 32){
    float di = dis[node];
    float4 b = ((const float4*)bias)[sl];
    float4 o;
    o.x = fmaxf(di*acc.x + b.x, 0.f);
    o.y = fmaxf(di*acc.y + b.y, 0.f);
    o.z = fmaxf(di*acc.z + b.z, 0.f);
    o.w = fmaxf(di*acc.w + b.w, 0.f);
    ((float4*)H)[(size_t)node*32 + sl] = o;
  }
}

// one wave per node; 3 groups x 20 lanes, 3-way unroll = 9 gathers in flight
__global__ __launch_bounds__(256)
void agg_softmax40(const float* __restrict__ T, const int* __restrict__ off,
                   const int* __restrict__ csr, const float* __restrict__ dis,
                   const float* __restrict__ bias, float* __restrict__ OUT, int N)
{
  int node = blockIdx.x*4 + (threadIdx.x >> 6);
  if(node >= N) return;
  int lane = threadIdx.x & 63;
  int g  = lane / 20;
  int sl = lane - g*20;
  int s = off[node], e = off[node+1];
  const float2* T2 = (const float2*)T;
  float ax = 0.f, ay = 0.f, bx = 0.f, by = 0.f, cx = 0.f, cy = 0.f;
  if(g < 3){
    int i = s + g;
    for(; i + 6 < e; i += 9){
      int u0 = csr[i], u1 = csr[i+3], u2 = csr[i+6];
      float2 v0 = T2[(size_t)u0*20 + sl];
      float2 v1 = T2[(size_t)u1*20 + sl];
      float2 v2 = T2[(size_t)u2*20 + sl];
      ax += v0.x; ay += v0.y;
      bx += v1.x; by += v1.y;
      cx += v2.x; cy += v2.y;
    }
    for(; i < e; i += 3){
      int u = csr[i];
      float2 v = T2[(size_t)u*20 + sl];
      ax += v.x; ay += v.y;
    }
    if(g == 0){
      float2 v = T2[(size_t)node*20 + sl];
      ax += v.x; ay += v.y;
    }
    ax += bx + cx; ay += by + cy;
  }
  ax += __shfl(ax, lane + 20, 64) + __shfl(ax, lane + 40, 64);
  ay += __shfl(ay, lane + 20, 64) + __shfl(ay, lane + 40, 64);
  float di = dis[node];
  float vx = -1e30f, vy = -1e30f;
  if(lane < 20){
    float2 b = ((const float2*)bias)[sl];
    vx = di*ax + b.x;
    vy = di*ay + b.y;
  }
  float m = fmaxf(vx, vy);
  #pragma unroll
  for(int o = 1; o < 32; o <<= 1) m = fmaxf(m, __shfl_xor(m, o, 32));
  float ex = (lane < 20) ? (expf(vx - m) + expf(vy - m)) : 0.f;
  float ssum = ex;
  #pragma unroll
  for(int o = 1; o < 32; o <<= 1) ssum += __shfl_xor(ssum, o, 32);
  float lse = m + logf(ssum);
  if(lane < 20){
    float2 o2; o2.x = vx - lse; o2.y = vy - lse;
    ((float2*)OUT)[(size_t)node*20 + sl] = o2;
  }
}

// ================= history overwrite: deterministic "last j wins" =================

__global__ void k_stamp(const int* __restrict__ idx_com, int* __restrict__ stamp, int n){
  int j = blockIdx.x*256 + threadIdx.x;
  if(j < n) atomicMax(&stamp[idx_com[j]], j);
}

__global__ __launch_bounds__(256)
void k_overwrite(const int* __restrict__ idx_com, const int* __restrict__ idx_data,
                 const int* __restrict__ stamp, const float* __restrict__ hist,
                 float* __restrict__ H, int n)
{
  int j = blockIdx.x*4 + (threadIdx.x >> 6);
  if(j >= n) return;
  int lane = threadIdx.x & 63;
  int c = idx_com[j];
  if(stamp[c] != j) return;
  int d = idx_data[j];
  ((float2*)H)[(size_t)c*64 + lane] = ((const float2*)hist)[(size_t)d*64 + lane];
}

// ================= launch =================

extern "C" void kernel_launch(void* const* d_in, const int* in_sizes, int n_in,
                              void* d_out, int out_size, void* d_ws, size_t ws_size,
                              hipStream_t stream)
{
  const float* x     = (const float*)d_in[0];
  const float* W0    = (const float*)d_in[1];
  const float* b0    = (const float*)d_in[2];
  const float* W1    = (const float*)d_in[3];
  const float* b1    = (const float*)d_in[4];
  const float* W2    = (const float*)d_in[5];
  const float* b2    = (const float*)d_in[6];
  const float* hist0 = (const float*)d_in[7];
  const float* hist1 = (const float*)d_in[8];
  const int* esrc = (const int*)d_in[9];
  const int* edst = (const int*)d_in[10];
  const int* idx_data0 = (const int*)d_in[11];
  const int* idx_com0  = (const int*)d_in[12];
  const int* idx_data1 = (const int*)d_in[13];
  const int* idx_com1  = (const int*)d_in[14];

  const int N  = in_sizes[0] / NFEAT;
  const int E  = in_sizes[9];
  const int NC = in_sizes[11];
  const int NB = (N + 127) / 128;

  char* p = (char*)d_ws;
  auto carve = [&](size_t bytes) -> void* {
    void* r = (void*)p;
    p += (bytes + 255) & ~(size_t)255;
    return r;
  };
  int*   bh    = (int*)  carve((size_t)NB*4);
  int*   boff  = (int*)  carve((size_t)(NB+1)*4);
  int*   bcur  = (int*)  carve((size_t)NB*4);
  int*   off   = (int*)  carve((size_t)(N+1)*4);
  int*   stamp = (int*)  carve((size_t)N*4);
  int*   csr   = (int*)  carve((size_t)E*4);
  float* dis   = (float*)carve((size_t)N*4);
  float* bufA  = (float*)carve((size_t)N*NHID*4);
  float* bufB  = (float*)carve((size_t)N*NHID*4);
  size_t cbytes = (size_t)N*NCLASS*4;
  size_t tbytes = (size_t)E*8;
  float* bufC  = (float*)carve(cbytes > tbytes ? cbytes : tbytes);
  int2*  tmp   = (int2*)bufC;

  // --- build CSR + degrees ---
  hipMemsetAsync(bh, 0, (size_t)NB*4, stream);
  P1_hist<<<256, 256, 0, stream>>>(edst, bh, E, NB);
  P2_scan<<<1, 1024, 0, stream>>>(bh, boff, bcur, off, N, E, NB);
  P3_part<<<(E + CHUNK - 1)/CHUNK, 256, 0, stream>>>(esrc, edst, bcur, tmp, E, NB);
  P4_build<<<NB, 256, 0, stream>>>(tmp, boff, off, dis, csr, N);

  // --- layer 0 ---
  gemm128_scale<NFEAT><<<dim3((N + 127)/128, 1), 256, 0, stream>>>(x, W0, dis, bufA, N);
  agg_relu128<<<(N+3)/4, 256, 0, stream>>>(bufA, off, csr, dis, b0, bufB, N);

  hipMemsetAsync(stamp, 0xFF, (size_t)N*4, stream);
  k_stamp<<<(NC+255)/256, 256, 0, stream>>>(idx_com0, stamp, NC);
  k_overwrite<<<(NC+3)/4, 256, 0, stream>>>(idx_com0, idx_data0, stamp, hist0, bufB, NC);

  // --- layer 1 ---
  gemm128_scale<NHID><<<dim3((N + 127)/128, 1), 256, 0, stream>>>(bufB, W1, dis, bufA, N);
  agg_relu128<<<(N+3)/4, 256, 0, stream>>>(bufA, off, csr, dis, b1, bufB, N);

  hipMemsetAsync(stamp, 0xFF, (size_t)N*4, stream);
  k_stamp<<<(NC+255)/256, 256, 0, stream>>>(idx_com1, stamp, NC);
  k_overwrite<<<(NC+3)/4, 256, 0, stream>>>(idx_com1, idx_data1, stamp, hist1, bufB, NC);

  // --- layer 2 + log_softmax ---
  gemm_scale<NHID, NCLASS><<<dim3((N + 127)/128, 1), 256, 0, stream>>>(bufB, W2, dis, bufC, N);
  agg_softmax40<<<(N+3)/4, 256, 0, stream>>>(bufC, off, csr, dis, b2, (float*)d_out, N);
}

// Round 5
// 732.872 us; speedup vs baseline: 1.3207x; 1.0610x over previous
//
#include <hip/hip_runtime.h>
#include <cmath>

#define NFEAT 256
#define NHID  128
#define NCLASS 40
#define MAXNB 800      // buckets of 128 nodes: ceil(100000/128)=782
#define CHUNK 8192

typedef __attribute__((ext_vector_type(8))) short bf16x8;
typedef __attribute__((ext_vector_type(4))) float f32x4;

// ---------------- bf16 split helpers ----------------
__device__ __forceinline__ unsigned short f2bf(float f){
  unsigned u = __float_as_uint(f);
  u += 0x7FFFu + ((u >> 16) & 1u);     // round-to-nearest-even
  return (unsigned short)(u >> 16);
}
__device__ __forceinline__ void fsplit(float f, unsigned short &h, unsigned short &l){
  h = f2bf(f);
  float fh = __uint_as_float(((unsigned)h) << 16);
  l = f2bf(f - fh);
}

// ================= graph preprocessing: bucketed CSR build =================

__global__ __launch_bounds__(256)
void P1_hist(const int* __restrict__ dst, int* __restrict__ bh, int E, int NB){
  __shared__ int lh[MAXNB];
  for(int t = threadIdx.x; t < NB; t += 256) lh[t] = 0;
  __syncthreads();
  for(int i = blockIdx.x*256 + threadIdx.x; i < E; i += gridDim.x*256)
    atomicAdd(&lh[dst[i] >> 7], 1);
  __syncthreads();
  for(int t = threadIdx.x; t < NB; t += 256){
    int c = lh[t];
    if(c) atomicAdd(&bh[t], c);
  }
}

__global__ __launch_bounds__(1024)
void P2_scan(const int* __restrict__ bh, int* __restrict__ boff, int* __restrict__ bcur,
             int* __restrict__ off, int N, int E, int NB){
  __shared__ int sc[1024];
  int t = threadIdx.x;
  int v = (t < NB) ? bh[t] : 0;
  sc[t] = v; __syncthreads();
  for(int o = 1; o < 1024; o <<= 1){
    int a = sc[t] + ((t >= o) ? sc[t-o] : 0);
    __syncthreads();
    sc[t] = a;
    __syncthreads();
  }
  int ex = sc[t] - v;
  if(t < NB){ boff[t] = ex; bcur[t] = ex; }
  if(t == 0){ boff[NB] = E; off[N] = E; }
}

__global__ __launch_bounds__(256)
void P3_part(const int* __restrict__ src, const int* __restrict__ dst,
             int* __restrict__ bcur, int2* __restrict__ tmp, int E, int NB){
  __shared__ int dstS[CHUNK];
  __shared__ int lh[MAXNB];
  __shared__ int lcur[MAXNB];
  int base = blockIdx.x * CHUNK;
  int n = E - base; if(n > CHUNK) n = CHUNK;
  for(int t = threadIdx.x; t < NB; t += 256){ lh[t] = 0; lcur[t] = 0; }
  __syncthreads();
  for(int j = threadIdx.x; j < n; j += 256){
    int d = dst[base + j];
    dstS[j] = d;
    atomicAdd(&lh[d >> 7], 1);
  }
  __syncthreads();
  for(int t = threadIdx.x; t < NB; t += 256){
    int c = lh[t];
    if(c) lh[t] = atomicAdd(&bcur[t], c);
  }
  __syncthreads();
  for(int j = threadIdx.x; j < n; j += 256){
    int d = dstS[j];
    int b = d >> 7;
    int p = lh[b] + atomicAdd(&lcur[b], 1);
    tmp[p] = make_int2(src[base + j], d);
  }
}

__global__ __launch_bounds__(256)
void P4_build(const int2* __restrict__ tmp, const int* __restrict__ boff,
              int* __restrict__ off, float* __restrict__ dis,
              int* __restrict__ csr, int N){
  __shared__ int2 eS[3072];
  __shared__ int cnt[128], sc[128], cur[128];
  int b = blockIdx.x;
  int s = boff[b], e = boff[b+1];
  int ne = e - s;
  int n0 = b * 128;
  if(threadIdx.x < 128){ cnt[threadIdx.x] = 0; cur[threadIdx.x] = 0; }
  __syncthreads();
  bool fits = (ne <= 3072);
  for(int i = threadIdx.x; i < ne; i += 256){
    int2 p = tmp[s + i];
    if(fits) eS[i] = p;
    atomicAdd(&cnt[p.y & 127], 1);
  }
  __syncthreads();
  if(threadIdx.x < 128) sc[threadIdx.x] = cnt[threadIdx.x];
  __syncthreads();
  for(int o = 1; o < 128; o <<= 1){
    int a = 0;
    if(threadIdx.x < 128) a = sc[threadIdx.x] + ((threadIdx.x >= o) ? sc[threadIdx.x - o] : 0);
    __syncthreads();
    if(threadIdx.x < 128) sc[threadIdx.x] = a;
    __syncthreads();
  }
  if(threadIdx.x < 128){
    int node = n0 + threadIdx.x;
    if(node < N){
      int c = cnt[threadIdx.x];
      off[node] = s + sc[threadIdx.x] - c;
      dis[node] = rsqrtf((float)(c + 1));
    }
  }
  __syncthreads();
  for(int i = threadIdx.x; i < ne; i += 256){
    int2 p = fits ? eS[i] : tmp[s + i];
    int l = p.y & 127;
    int pos = s + (sc[l] - cnt[l]) + atomicAdd(&cur[l], 1);
    csr[pos] = p.x;
  }
}

// ================= weight pre-transpose + bf16 hi/lo split =================
// W [K][NOUT] fp32 -> WTh/WTl [BNp][K] bf16 (cols >= NOUT zero-padded)

__global__ void k_wsplit(const float* __restrict__ W, unsigned short* __restrict__ WTh,
                         unsigned short* __restrict__ WTl, int K, int NOUT){
  int n = blockIdx.x;
  for(int k = threadIdx.x; k < K; k += blockDim.x){
    float f = (n < NOUT) ? W[(size_t)k*NOUT + n] : 0.f;
    unsigned short h, l;
    fsplit(f, h, l);
    WTh[(size_t)n*K + k] = h;
    WTl[(size_t)n*K + k] = l;
  }
}

// ================= MFMA GEMM (split-bf16, fp32-class accuracy) =================
// C[M x NOUT] = A[M x K] @ W[K x NOUT], row r scaled by dis[r].
// WT pre-transposed/split to [BN][K] bf16 hi/lo. A split inline while staging.
// Fragment k-indexing identical for A and B => hardware k-permutation cancels.

template<int K, int BN>
__global__ __launch_bounds__(256, 2)
void gemm_mfma_scale(const float* __restrict__ A,
                     const unsigned short* __restrict__ WTh,
                     const unsigned short* __restrict__ WTl,
                     const float* __restrict__ dis,
                     float* __restrict__ C, int M, int NOUT)
{
  constexpr int BM = 128, BK = 32;
  constexpr int WM = (BN == 128) ? 64 : 32;   // per-wave rows
  constexpr int WN = 64;                      // per-wave cols
  constexpr int NWN = BN / WN;                // waves across N
  constexpr int MF = WM / 16, NF = WN / 16;
  __shared__ __align__(16) unsigned short AsH[BM][BK];
  __shared__ __align__(16) unsigned short AsL[BM][BK];
  __shared__ __align__(16) unsigned short WsH[BN][BK];
  __shared__ __align__(16) unsigned short WsL[BN][BK];

  const int tid  = threadIdx.x;
  const int wave = tid >> 6;
  const int lane = tid & 63;
  const int wm = wave / NWN;
  const int wn = wave % NWN;
  const int m0 = blockIdx.x * BM;
  const int lr = lane & 15;    // A-row / B-col within fragment
  const int lg = lane >> 4;    // k-group

  f32x4 acc[MF][NF];
  #pragma unroll
  for(int i = 0; i < MF; i++)
    #pragma unroll
    for(int j = 0; j < NF; j++)
      acc[i][j] = (f32x4){0.f,0.f,0.f,0.f};

  for(int k0 = 0; k0 < K; k0 += BK){
    // stage A tile 128x32 fp32 -> hi/lo bf16
    #pragma unroll
    for(int j = 0; j < 4; j++){
      int s   = tid + j*256;       // 0..1023
      int row = s >> 3;
      int kq  = (s & 7) * 4;
      float4 v = {0.f,0.f,0.f,0.f};
      if(m0 + row < M) v = *reinterpret_cast<const float4*>(&A[(size_t)(m0+row)*K + k0 + kq]);
      ushort4 h, l;
      fsplit(v.x, h.x, l.x); fsplit(v.y, h.y, l.y);
      fsplit(v.z, h.z, l.z); fsplit(v.w, h.w, l.w);
      *reinterpret_cast<ushort4*>(&AsH[row][kq]) = h;
      *reinterpret_cast<ushort4*>(&AsL[row][kq]) = l;
    }
    // stage W tiles (already bf16): BN x 32 each, 16B copies
    constexpr int WSLOTS = BN * BK / 8;
    #pragma unroll
    for(int s = 0; s < WSLOTS; s += 256){
      int ss = s + tid;
      int n  = ss >> 2;
      int kq = (ss & 3) * 8;
      *reinterpret_cast<uint4*>(&WsH[n][kq]) =
          *reinterpret_cast<const uint4*>(&WTh[(size_t)n*K + k0 + kq]);
      *reinterpret_cast<uint4*>(&WsL[n][kq]) =
          *reinterpret_cast<const uint4*>(&WTl[(size_t)n*K + k0 + kq]);
    }
    __syncthreads();

    bf16x8 ah[MF], al[MF], bh[NF], bl[NF];
    #pragma unroll
    for(int i = 0; i < MF; i++){
      ah[i] = *reinterpret_cast<const bf16x8*>(&AsH[wm*WM + i*16 + lr][lg*8]);
      al[i] = *reinterpret_cast<const bf16x8*>(&AsL[wm*WM + i*16 + lr][lg*8]);
    }
    #pragma unroll
    for(int j = 0; j < NF; j++){
      bh[j] = *reinterpret_cast<const bf16x8*>(&WsH[wn*WN + j*16 + lr][lg*8]);
      bl[j] = *reinterpret_cast<const bf16x8*>(&WsL[wn*WN + j*16 + lr][lg*8]);
    }
    #pragma unroll
    for(int i = 0; i < MF; i++)
      #pragma unroll
      for(int j = 0; j < NF; j++){
        acc[i][j] = __builtin_amdgcn_mfma_f32_16x16x32_bf16(ah[i], bh[j], acc[i][j], 0, 0, 0);
        acc[i][j] = __builtin_amdgcn_mfma_f32_16x16x32_bf16(ah[i], bl[j], acc[i][j], 0, 0, 0);
        acc[i][j] = __builtin_amdgcn_mfma_f32_16x16x32_bf16(al[i], bh[j], acc[i][j], 0, 0, 0);
      }
    __syncthreads();
  }

  // epilogue: D row = (lane>>4)*4 + reg, col = lane&15 (HW-verified layout)
  #pragma unroll
  for(int i = 0; i < MF; i++){
    int rbase = m0 + wm*WM + i*16 + lg*4;
    #pragma unroll
    for(int r = 0; r < 4; r++){
      int row = rbase + r;
      if(row >= M) continue;
      float d = dis[row];
      #pragma unroll
      for(int j = 0; j < NF; j++){
        int col = wn*WN + j*16 + lr;
        if(col < NOUT)
          C[(size_t)row*NOUT + col] = acc[i][j][r] * d;
      }
    }
  }
}

// ================= aggregation =================

__global__ __launch_bounds__(256)
void agg_relu128(const float* __restrict__ T, const int* __restrict__ off,
                 const int* __restrict__ csr, const float* __restrict__ dis,
                 const float* __restrict__ bias, float* __restrict__ H, int N)
{
  int node = blockIdx.x*4 + (threadIdx.x >> 6);
  if(node >= N) return;
  int lane = threadIdx.x & 63;
  int half = lane >> 5;
  int sl = lane & 31;
  int s = off[node], e = off[node+1];
  const float4* T4 = (const float4*)T;
  float4 a0 = {0.f,0.f,0.f,0.f}, a1 = a0, a2 = a0, a3 = a0;
  int i = s + half;
  for(; i + 6 < e; i += 8){
    int u0 = csr[i], u1 = csr[i+2], u2 = csr[i+4], u3 = csr[i+6];
    float4 v0 = T4[(size_t)u0*32 + sl];
    float4 v1 = T4[(size_t)u1*32 + sl];
    float4 v2 = T4[(size_t)u2*32 + sl];
    float4 v3 = T4[(size_t)u3*32 + sl];
    a0.x += v0.x; a0.y += v0.y; a0.z += v0.z; a0.w += v0.w;
    a1.x += v1.x; a1.y += v1.y; a1.z += v1.z; a1.w += v1.w;
    a2.x += v2.x; a2.y += v2.y; a2.z += v2.z; a2.w += v2.w;
    a3.x += v3.x; a3.y += v3.y; a3.z += v3.z; a3.w += v3.w;
  }
  for(; i < e; i += 2){
    int u = csr[i];
    float4 v = T4[(size_t)u*32 + sl];
    a0.x += v.x; a0.y += v.y; a0.z += v.z; a0.w += v.w;
  }
  if(half == 0){
    float4 v = T4[(size_t)node*32 + sl];
    a0.x += v.x; a0.y += v.y; a0.z += v.z; a0.w += v.w;
  }
  float4 acc;
  acc.x = a0.x + a1.x + a2.x + a3.x;
  acc.y = a0.y + a1.y + a2.y + a3.y;
  acc.z = a0.z + a1.z + a2.z + a3.z;
  acc.w = a0.w + a1.w + a2.w + a3.w;
  acc.x += __shfl_down(acc.x, 32, 64);
  acc.y += __shfl_down(acc.y, 32, 64);
  acc.z += __shfl_down(acc.z, 32, 64);
  acc.w += __shfl_down(acc.w, 32, 64);
  if(lane < 32){
    float di = dis[node];
    float4 b = ((const float4*)bias)[sl];
    float4 o;
    o.x = fmaxf(di*acc.x + b.x, 0.f);
    o.y = fmaxf(di*acc.y + b.y, 0.f);
    o.z = fmaxf(di*acc.z + b.z, 0.f);
    o.w = fmaxf(di*acc.w + b.w, 0.f);
    ((float4*)H)[(size_t)node*32 + sl] = o;
  }
}

__global__ __launch_bounds__(256)
void agg_softmax40(const float* __restrict__ T, const int* __restrict__ off,
                   const int* __restrict__ csr, const float* __restrict__ dis,
                   const float* __restrict__ bias, float* __restrict__ OUT, int N)
{
  int node = blockIdx.x*4 + (threadIdx.x >> 6);
  if(node >= N) return;
  int lane = threadIdx.x & 63;
  int g  = lane / 20;
  int sl = lane - g*20;
  int s = off[node], e = off[node+1];
  const float2* T2 = (const float2*)T;
  float ax = 0.f, ay = 0.f, bx = 0.f, by = 0.f, cx = 0.f, cy = 0.f;
  if(g < 3){
    int i = s + g;
    for(; i + 6 < e; i += 9){
      int u0 = csr[i], u1 = csr[i+3], u2 = csr[i+6];
      float2 v0 = T2[(size_t)u0*20 + sl];
      float2 v1 = T2[(size_t)u1*20 + sl];
      float2 v2 = T2[(size_t)u2*20 + sl];
      ax += v0.x; ay += v0.y;
      bx += v1.x; by += v1.y;
      cx += v2.x; cy += v2.y;
    }
    for(; i < e; i += 3){
      int u = csr[i];
      float2 v = T2[(size_t)u*20 + sl];
      ax += v.x; ay += v.y;
    }
    if(g == 0){
      float2 v = T2[(size_t)node*20 + sl];
      ax += v.x; ay += v.y;
    }
    ax += bx + cx; ay += by + cy;
  }
  ax += __shfl(ax, lane + 20, 64) + __shfl(ax, lane + 40, 64);
  ay += __shfl(ay, lane + 20, 64) + __shfl(ay, lane + 40, 64);
  float di = dis[node];
  float vx = -1e30f, vy = -1e30f;
  if(lane < 20){
    float2 b = ((const float2*)bias)[sl];
    vx = di*ax + b.x;
    vy = di*ay + b.y;
  }
  float m = fmaxf(vx, vy);
  #pragma unroll
  for(int o = 1; o < 32; o <<= 1) m = fmaxf(m, __shfl_xor(m, o, 32));
  float ex = (lane < 20) ? (expf(vx - m) + expf(vy - m)) : 0.f;
  float ssum = ex;
  #pragma unroll
  for(int o = 1; o < 32; o <<= 1) ssum += __shfl_xor(ssum, o, 32);
  float lse = m + logf(ssum);
  if(lane < 20){
    float2 o2; o2.x = vx - lse; o2.y = vy - lse;
    ((float2*)OUT)[(size_t)node*20 + sl] = o2;
  }
}

// ================= history overwrite: deterministic "last j wins" =================

__global__ void k_stamp(const int* __restrict__ idx_com, int* __restrict__ stamp, int n){
  int j = blockIdx.x*256 + threadIdx.x;
  if(j < n) atomicMax(&stamp[idx_com[j]], j);
}

__global__ __launch_bounds__(256)
void k_overwrite(const int* __restrict__ idx_com, const int* __restrict__ idx_data,
                 const int* __restrict__ stamp, const float* __restrict__ hist,
                 float* __restrict__ H, int n)
{
  int j = blockIdx.x*4 + (threadIdx.x >> 6);
  if(j >= n) return;
  int lane = threadIdx.x & 63;
  int c = idx_com[j];
  if(stamp[c] != j) return;
  int d = idx_data[j];
  ((float2*)H)[(size_t)c*64 + lane] = ((const float2*)hist)[(size_t)d*64 + lane];
}

// ================= launch =================

extern "C" void kernel_launch(void* const* d_in, const int* in_sizes, int n_in,
                              void* d_out, int out_size, void* d_ws, size_t ws_size,
                              hipStream_t stream)
{
  const float* x     = (const float*)d_in[0];
  const float* W0    = (const float*)d_in[1];
  const float* b0    = (const float*)d_in[2];
  const float* W1    = (const float*)d_in[3];
  const float* b1    = (const float*)d_in[4];
  const float* W2    = (const float*)d_in[5];
  const float* b2    = (const float*)d_in[6];
  const float* hist0 = (const float*)d_in[7];
  const float* hist1 = (const float*)d_in[8];
  const int* esrc = (const int*)d_in[9];
  const int* edst = (const int*)d_in[10];
  const int* idx_data0 = (const int*)d_in[11];
  const int* idx_com0  = (const int*)d_in[12];
  const int* idx_data1 = (const int*)d_in[13];
  const int* idx_com1  = (const int*)d_in[14];

  const int N  = in_sizes[0] / NFEAT;
  const int E  = in_sizes[9];
  const int NC = in_sizes[11];
  const int NB = (N + 127) / 128;

  char* p = (char*)d_ws;
  auto carve = [&](size_t bytes) -> void* {
    void* r = (void*)p;
    p += (bytes + 255) & ~(size_t)255;
    return r;
  };
  int*   bh    = (int*)  carve((size_t)NB*4);
  int*   boff  = (int*)  carve((size_t)(NB+1)*4);
  int*   bcur  = (int*)  carve((size_t)NB*4);
  int*   off   = (int*)  carve((size_t)(N+1)*4);
  int*   stamp = (int*)  carve((size_t)N*4);
  int*   csr   = (int*)  carve((size_t)E*4);
  float* dis   = (float*)carve((size_t)N*4);
  unsigned short* w0h = (unsigned short*)carve((size_t)128*256*2);
  unsigned short* w0l = (unsigned short*)carve((size_t)128*256*2);
  unsigned short* w1h = (unsigned short*)carve((size_t)128*128*2);
  unsigned short* w1l = (unsigned short*)carve((size_t)128*128*2);
  unsigned short* w2h = (unsigned short*)carve((size_t)64*128*2);
  unsigned short* w2l = (unsigned short*)carve((size_t)64*128*2);
  float* bufA  = (float*)carve((size_t)N*NHID*4);
  float* bufB  = (float*)carve((size_t)N*NHID*4);
  size_t cbytes = (size_t)N*NCLASS*4;
  size_t tbytes = (size_t)E*8;
  float* bufC  = (float*)carve(cbytes > tbytes ? cbytes : tbytes);
  int2*  tmp   = (int2*)bufC;

  // --- weight transpose + split (independent; tiny) ---
  k_wsplit<<<128, 256, 0, stream>>>(W0, w0h, w0l, NFEAT, NHID);
  k_wsplit<<<128, 256, 0, stream>>>(W1, w1h, w1l, NHID, NHID);
  k_wsplit<<< 64, 256, 0, stream>>>(W2, w2h, w2l, NHID, NCLASS);

  // --- build CSR + degrees ---
  hipMemsetAsync(bh, 0, (size_t)NB*4, stream);
  P1_hist<<<256, 256, 0, stream>>>(edst, bh, E, NB);
  P2_scan<<<1, 1024, 0, stream>>>(bh, boff, bcur, off, N, E, NB);
  P3_part<<<(E + CHUNK - 1)/CHUNK, 256, 0, stream>>>(esrc, edst, bcur, tmp, E, NB);
  P4_build<<<NB, 256, 0, stream>>>(tmp, boff, off, dis, csr, N);

  // --- layer 0 ---
  gemm_mfma_scale<NFEAT, 128><<<NB, 256, 0, stream>>>(x, w0h, w0l, dis, bufA, N, NHID);
  agg_relu128<<<(N+3)/4, 256, 0, stream>>>(bufA, off, csr, dis, b0, bufB, N);

  hipMemsetAsync(stamp, 0xFF, (size_t)N*4, stream);
  k_stamp<<<(NC+255)/256, 256, 0, stream>>>(idx_com0, stamp, NC);
  k_overwrite<<<(NC+3)/4, 256, 0, stream>>>(idx_com0, idx_data0, stamp, hist0, bufB, NC);

  // --- layer 1 ---
  gemm_mfma_scale<NHID, 128><<<NB, 256, 0, stream>>>(bufB, w1h, w1l, dis, bufA, N, NHID);
  agg_relu128<<<(N+3)/4, 256, 0, stream>>>(bufA, off, csr, dis, b1, bufB, N);

  hipMemsetAsync(stamp, 0xFF, (size_t)N*4, stream);
  k_stamp<<<(NC+255)/256, 256, 0, stream>>>(idx_com1, stamp, NC);
  k_overwrite<<<(NC+3)/4, 256, 0, stream>>>(idx_com1, idx_data1, stamp, hist1, bufB, NC);

  // --- layer 2 + log_softmax ---
  gemm_mfma_scale<NHID, 64><<<NB, 256, 0, stream>>>(bufB, w2h, w2l, dis, bufC, N, NCLASS);
  agg_softmax40<<<(N+3)/4, 256, 0, stream>>>(bufC, off, csr, dis, b2, (float*)d_out, N);
}